// Round 13
// baseline (741.951 us; speedup 1.0000x reference)
//
#include <hip/hip_runtime.h>

#define F    128   // in/out features
#define PAD  64    // padded adjacency slots per node (row-major: padded[d*PAD+p])
#define GRID 1024  // persistent blocks: 128 slices x 8 XCDs; 4 blocks/CU guaranteed resident

typedef short short8 __attribute__((ext_vector_type(8)));
typedef float f32x4v __attribute__((ext_vector_type(4)));

__device__ __forceinline__ ushort f2bf(float f) {
    uint b = __float_as_uint(f);
    uint r = (b + 0x7fffu + ((b >> 16) & 1u)) >> 16;
    return (ushort)r;
}
__device__ __forceinline__ float bflo(uint v) { return __uint_as_float(v << 16); }
__device__ __forceinline__ float bfhi(uint v) { return __uint_as_float(v & 0xffff0000u); }

// Sense-reversing grid barrier. gen monotonic within a call; {ctr,gen} zeroed by a
// 16B memsetAsync before each launch (handles harness 0xAA ws poison). All GRID
// blocks are co-resident by capacity construction (see launch_bounds + grid math).
__device__ __forceinline__ void grid_barrier(unsigned* ctr, unsigned long long* gen) {
    __syncthreads();
    __threadfence();                                   // release: device-scope visibility
    if (threadIdx.x == 0) {
        unsigned long long g0 =
            __hip_atomic_load(gen, __ATOMIC_RELAXED, __HIP_MEMORY_SCOPE_AGENT);
        unsigned a =
            __hip_atomic_fetch_add(ctr, 1u, __ATOMIC_ACQ_REL, __HIP_MEMORY_SCOPE_AGENT);
        if (a + 1u == (unsigned)GRID) {
            __hip_atomic_store(ctr, 0u, __ATOMIC_RELAXED, __HIP_MEMORY_SCOPE_AGENT);
            __hip_atomic_fetch_add(gen, 1ull, __ATOMIC_RELEASE, __HIP_MEMORY_SCOPE_AGENT);
        } else {
            while (__hip_atomic_load(gen, __ATOMIC_RELAXED, __HIP_MEMORY_SCOPE_AGENT) == g0)
                __builtin_amdgcn_s_sleep(2);
        }
    }
    __syncthreads();
    __threadfence();                                   // acquire: drop stale L2 lines
}

// ---------------- fused persistent kernel: zero -> bucket -> gemm -> gather ----------------

__global__ __launch_bounds__(256, 4) void fused(
    const int* __restrict__ src, const int* __restrict__ dst, int ne,
    const float* __restrict__ x, const float* __restrict__ w,
    const float* __restrict__ bias,
    int* __restrict__ cnt, ushort* __restrict__ padded, ushort* __restrict__ g,
    float* __restrict__ out,
    unsigned* __restrict__ ctr, unsigned long long* __restrict__ gen,
    int n, int nbG)
{
    const int bid = blockIdx.x;
    const int tid = threadIdx.x;

    // ---- P0: zero cnt ----
    for (int i = bid * 256 + tid; i < n; i += GRID * 256) cnt[i] = 0;
    grid_barrier(ctr, gen);

    // ---- P1: bucket — XCD-partitioned padded-CSR build (R11 scheme, co-residency now provable)
    {
        const int xcd   = bid & 7;
        const int slice = bid >> 3;
        const int nsl   = GRID >> 3;                      // 128 slices
        int chunk = ((ne + nsl - 1) / nsl + 3) & ~3;      // int4-aligned
        const int sh  = (n + 7) >> 3;
        const int dlo = xcd * sh;
        const int dhi = (dlo + sh) < n ? (dlo + sh) : n;
        const int base = slice * chunk;
        const int lim  = (base + chunk) < ne ? (base + chunk) : ne;

        for (int e0 = base + tid * 4; e0 < lim; e0 += 1024) {
            if (e0 + 3 < lim) {
                int4 s4 = *reinterpret_cast<const int4*>(&src[e0]);
                int4 d4 = *reinterpret_cast<const int4*>(&dst[e0]);
                if (d4.x >= dlo && d4.x < dhi) {
                    int p = atomicAdd(&cnt[d4.x], 1);
                    if (p < PAD) padded[(size_t)d4.x * PAD + p] = (ushort)s4.x;
                }
                if (d4.y >= dlo && d4.y < dhi) {
                    int p = atomicAdd(&cnt[d4.y], 1);
                    if (p < PAD) padded[(size_t)d4.y * PAD + p] = (ushort)s4.y;
                }
                if (d4.z >= dlo && d4.z < dhi) {
                    int p = atomicAdd(&cnt[d4.z], 1);
                    if (p < PAD) padded[(size_t)d4.z * PAD + p] = (ushort)s4.z;
                }
                if (d4.w >= dlo && d4.w < dhi) {
                    int p = atomicAdd(&cnt[d4.w], 1);
                    if (p < PAD) padded[(size_t)d4.w * PAD + p] = (ushort)s4.w;
                }
            } else {
                for (int e = e0; e < lim; ++e) {
                    int d = dst[e];
                    if (d >= dlo && d < dhi) {
                        int p = atomicAdd(&cnt[d], 1);
                        if (p < PAD) padded[(size_t)d * PAD + p] = (ushort)src[e];
                    }
                }
            }
        }
    }
    grid_barrier(ctr, gen);

    // ---- P2: gemm — g[row] = bf16( dinv[row] * (x@W)[row] ); one 64-row tile per block ----
    if (bid < nbG) {
        const int lane = tid & 63;
        const int wv   = tid >> 6;
        const int wr   = wv >> 1, wc = wv & 1;
        const int l15  = lane & 15, kg = lane >> 4;
        const int row0 = bid * 64 + wr * 32;
        const int col0 = wc * 64;

        f32x4v acc[2][4];
        #pragma unroll
        for (int rt = 0; rt < 2; ++rt)
            #pragma unroll
            for (int ct = 0; ct < 4; ++ct)
                acc[rt][ct] = (f32x4v){0.f, 0.f, 0.f, 0.f};

        #pragma unroll
        for (int kt = 0; kt < 4; ++kt) {
            const int k0 = kt * 32 + kg * 8;
            short8 a[2];
            #pragma unroll
            for (int rt = 0; rt < 2; ++rt) {
                int row = row0 + rt * 16 + l15;
                row = row < n ? row : n - 1;               // clamp (stores guarded)
                float4 p0 = *reinterpret_cast<const float4*>(&x[(size_t)row * F + k0]);
                float4 p1 = *reinterpret_cast<const float4*>(&x[(size_t)row * F + k0 + 4]);
                ushort u[8] = {f2bf(p0.x), f2bf(p0.y), f2bf(p0.z), f2bf(p0.w),
                               f2bf(p1.x), f2bf(p1.y), f2bf(p1.z), f2bf(p1.w)};
                a[rt] = *reinterpret_cast<short8*>(u);
            }
            short8 b[4];
            #pragma unroll
            for (int ct = 0; ct < 4; ++ct) {
                int col = col0 + ct * 16 + l15;
                ushort u[8];
                #pragma unroll
                for (int j = 0; j < 8; ++j)
                    u[j] = f2bf(w[(size_t)(k0 + j) * F + col]);
                b[ct] = *reinterpret_cast<short8*>(u);
            }
            #pragma unroll
            for (int rt = 0; rt < 2; ++rt)
                #pragma unroll
                for (int ct = 0; ct < 4; ++ct)
                    acc[rt][ct] = __builtin_amdgcn_mfma_f32_16x16x32_bf16(
                        a[rt], b[ct], acc[rt][ct], 0, 0, 0);
        }

        #pragma unroll
        for (int rt = 0; rt < 2; ++rt) {
            int rbase = row0 + rt * 16 + kg * 4;
            float dv[4];
            #pragma unroll
            for (int rr = 0; rr < 4; ++rr) {
                int ri = rbase + rr < n ? rbase + rr : n - 1;
                dv[rr] = rsqrtf((float)cnt[ri] + 1.0f);
            }
            #pragma unroll
            for (int ct = 0; ct < 4; ++ct) {
                int col = col0 + ct * 16 + l15;
                #pragma unroll
                for (int rr = 0; rr < 4; ++rr) {
                    int row = rbase + rr;
                    if (row < n)
                        g[(size_t)row * F + col] = f2bf(acc[rt][ct][rr] * dv[rr]);
                }
            }
        }
    }
    grid_barrier(ctr, gen);

    // ---- P3: gather — persistent waves, grid-stride over nodes ----
    {
        const int nwaves = GRID * 4;
        const int lane   = tid & 63;
        const int c      = lane * 2;
        for (int wid0 = bid * 4 + (tid >> 6); wid0 < n; wid0 += nwaves) {
            int wid = __builtin_amdgcn_readfirstlane(wid0);   // wave-uniform -> SGPR

            int   cv = cnt[wid];
            float dv = rsqrtf((float)cv + 1.0f);
            uint self = *reinterpret_cast<const uint*>(&g[(size_t)wid * F + c]);
            float ax = bflo(self), ay = bfhi(self);

            int m = cv < PAD ? cv : PAD;
            const ushort* pl = padded + (size_t)wid * PAD;

            int j = 0;
            for (; j + 8 <= m; j += 8) {
                uint4 pk = *reinterpret_cast<const uint4*>(&pl[j]);
                int s0 = (int)(pk.x & 0xffffu), s1 = (int)(pk.x >> 16);
                int s2 = (int)(pk.y & 0xffffu), s3 = (int)(pk.y >> 16);
                int s4 = (int)(pk.z & 0xffffu), s5 = (int)(pk.z >> 16);
                int s6 = (int)(pk.w & 0xffffu), s7 = (int)(pk.w >> 16);
                uint v0 = *reinterpret_cast<const uint*>(&g[(size_t)s0 * F + c]);
                uint v1 = *reinterpret_cast<const uint*>(&g[(size_t)s1 * F + c]);
                uint v2 = *reinterpret_cast<const uint*>(&g[(size_t)s2 * F + c]);
                uint v3 = *reinterpret_cast<const uint*>(&g[(size_t)s3 * F + c]);
                uint v4 = *reinterpret_cast<const uint*>(&g[(size_t)s4 * F + c]);
                uint v5 = *reinterpret_cast<const uint*>(&g[(size_t)s5 * F + c]);
                uint v6 = *reinterpret_cast<const uint*>(&g[(size_t)s6 * F + c]);
                uint v7 = *reinterpret_cast<const uint*>(&g[(size_t)s7 * F + c]);
                ax += ((bflo(v0) + bflo(v1)) + (bflo(v2) + bflo(v3)))
                    + ((bflo(v4) + bflo(v5)) + (bflo(v6) + bflo(v7)));
                ay += ((bfhi(v0) + bfhi(v1)) + (bfhi(v2) + bfhi(v3)))
                    + ((bfhi(v4) + bfhi(v5)) + (bfhi(v6) + bfhi(v7)));
            }
            for (; j < m; ++j) {
                int s = pl[j];
                uint v = *reinterpret_cast<const uint*>(&g[(size_t)s * F + c]);
                ax += bflo(v);
                ay += bfhi(v);
            }

            float2 bb = *reinterpret_cast<const float2*>(&bias[c]);
            float2 o;
            o.x = fmaf(dv, ax, bb.x);
            o.y = fmaf(dv, ay, bb.y);
            *reinterpret_cast<float2*>(&out[(size_t)wid * F + c]) = o;
        }
    }
}

// ---------------- fallback path (fp32 atomics, minimal ws) ----------------

__global__ __launch_bounds__(256) void gemm_scale(
    const float* __restrict__ x, const float* __restrict__ w,
    const float* __restrict__ dinv, float* __restrict__ g, int n)
{
    __shared__ float sWl[F * F];
    __shared__ float sXl[8][F];
    for (int i = threadIdx.x; i < F * F; i += 256) sWl[i] = w[i];
    __syncthreads();
    const int r  = threadIdx.x >> 5;
    const int cg = threadIdx.x & 31;
    for (int row0 = blockIdx.x * 8; row0 < n; row0 += gridDim.x * 8) {
        {
            int t4 = threadIdx.x * 4;
            int rr = t4 >> 7, cc = t4 & (F - 1);
            if (row0 + rr < n) {
                float4 v = *reinterpret_cast<const float4*>(&x[(size_t)(row0 + rr) * F + cc]);
                *reinterpret_cast<float4*>(&sXl[rr][cc]) = v;
            }
        }
        __syncthreads();
        int row = row0 + r;
        if (row < n) {
            float4 acc = make_float4(0.f, 0.f, 0.f, 0.f);
            const float* xr = sXl[r];
            #pragma unroll 8
            for (int k = 0; k < F; ++k) {
                float  xv = xr[k];
                float4 wv = *reinterpret_cast<const float4*>(&sWl[k * F + cg * 4]);
                acc.x = fmaf(xv, wv.x, acc.x);
                acc.y = fmaf(xv, wv.y, acc.y);
                acc.z = fmaf(xv, wv.z, acc.z);
                acc.w = fmaf(xv, wv.w, acc.w);
            }
            float s = dinv[row];
            acc.x *= s; acc.y *= s; acc.z *= s; acc.w *= s;
            *reinterpret_cast<float4*>(&g[(size_t)row * F + cg * 4]) = acc;
        }
        __syncthreads();
    }
}

__global__ void init_degf(float* __restrict__ deg, int n) {
    int i = blockIdx.x * blockDim.x + threadIdx.x;
    if (i < n) deg[i] = 1.0f;
}
__global__ void count_degf(const int* __restrict__ dst, int ne, float* __restrict__ deg) {
    int e = blockIdx.x * blockDim.x + threadIdx.x;
    if (e < ne) atomicAdd(&deg[dst[e]], 1.0f);
}
__global__ void calc_dinvf(const float* __restrict__ deg, float* __restrict__ dinv, int n) {
    int i = blockIdx.x * blockDim.x + threadIdx.x;
    if (i < n) dinv[i] = rsqrtf(fmaxf(deg[i], 1e-12f));
}
__global__ __launch_bounds__(256) void scatter_edges(
    const int* __restrict__ src, const int* __restrict__ dst, int ne,
    const float* __restrict__ g, float* __restrict__ out)
{
    int gid  = (blockIdx.x * blockDim.x + threadIdx.x) >> 5;
    int lane = threadIdx.x & 31;
    if (gid >= ne) return;
    int s = src[gid], d = dst[gid];
    float4 v = *reinterpret_cast<const float4*>(&g[(size_t)s * F + lane * 4]);
    float* op = &out[(size_t)d * F + lane * 4];
    atomicAdd(op + 0, v.x);
    atomicAdd(op + 1, v.y);
    atomicAdd(op + 2, v.z);
    atomicAdd(op + 3, v.w);
}
__global__ __launch_bounds__(256) void finalize(
    float* __restrict__ out, const float* __restrict__ g,
    const float* __restrict__ dinv, const float* __restrict__ bias, int n)
{
    int i = blockIdx.x * blockDim.x + threadIdx.x;
    if (i >= n * 32) return;
    int row = i >> 5, c4 = i & 31;
    float  s = dinv[row];
    float4 o = *reinterpret_cast<float4*>(&out[(size_t)i * 4]);
    float4 gg = *reinterpret_cast<const float4*>(&g[(size_t)i * 4]);
    float4 b = *reinterpret_cast<const float4*>(&bias[c4 * 4]);
    o.x = fmaf(s, o.x + gg.x, b.x);
    o.y = fmaf(s, o.y + gg.y, b.y);
    o.z = fmaf(s, o.z + gg.z, b.z);
    o.w = fmaf(s, o.w + gg.w, b.w);
    *reinterpret_cast<float4*>(&out[(size_t)i * 4]) = o;
}

// ---------------- launcher ----------------

extern "C" void kernel_launch(void* const* d_in, const int* in_sizes, int n_in,
                              void* d_out, int out_size, void* d_ws, size_t ws_size,
                              hipStream_t stream) {
    const float* x     = (const float*)d_in[0];
    const int*   index = (const int*)d_in[1];
    const float* w     = (const float*)d_in[2];
    const float* bias  = (const float*)d_in[3];
    float*       out   = (float*)d_out;

    int n  = in_sizes[0] / F;   // 50000
    int ne = in_sizes[1] / 2;   // 625000
    const int* src = index;
    const int* dst = index + ne;

    // workspace layout (bytes): [bar 16][cnt n*4][padded n*PAD*2][g n*F*2]
    size_t b_bar    = 0;
    size_t b_cnt    = 16;
    size_t b_padded = (b_cnt + (size_t)n * 4 + 15) & ~(size_t)15;
    size_t b_g      = (b_padded + (size_t)n * PAD * 2 + 15) & ~(size_t)15;
    size_t need     = b_g + (size_t)n * F * 2;

    char* wsb = (char*)d_ws;
    unsigned*           ctr    = (unsigned*)(wsb + b_bar);
    unsigned long long* gen    = (unsigned long long*)(wsb + b_bar + 8);
    int*                cnt    = (int*)(wsb + b_cnt);
    ushort*             padded = (ushort*)(wsb + b_padded);
    ushort*             g      = (ushort*)(wsb + b_g);

    int nbG = (n + 63) / 64;      // 782 gemm tiles (< GRID)

    if (ws_size >= need && n <= 65535 && nbG <= GRID) {
        hipMemsetAsync(wsb + b_bar, 0, 16, stream);
        fused<<<GRID, 256, 0, stream>>>(src, dst, ne, x, w, bias,
                                        cnt, padded, g, out, ctr, gen, n, nbG);
    } else {
        // fallback: fp32 atomic path
        float* degf  = (float*)wsb;
        float* dinvf = (float*)wsb + n;
        float* gf    = (float*)wsb + 2 * n;
        int nb  = (n + 255) / 256;
        int nbE = (ne + 255) / 256;
        hipMemsetAsync(d_out, 0, (size_t)out_size * sizeof(float), stream);
        init_degf<<<nb, 256, 0, stream>>>(degf, n);
        count_degf<<<nbE, 256, 0, stream>>>(dst, ne, degf);
        calc_dinvf<<<nb, 256, 0, stream>>>(degf, dinvf, n);
        gemm_scale<<<(n + 7) / 8, 256, 0, stream>>>(x, w, dinvf, gf, n);
        int sc_blocks = (int)(((long long)ne * 32 + 255) / 256);
        scatter_edges<<<sc_blocks, 256, 0, stream>>>(src, dst, ne, gf, out);
        finalize<<<(n * 32 + 255) / 256, 256, 0, stream>>>(out, gf, dinvf, bias, n);
    }
}

// Round 14
// 99.492 us; speedup vs baseline: 7.4574x; 7.4574x over previous
//
#include <hip/hip_runtime.h>

#define F     128   // in/out features
#define PAD   64    // padded adjacency slots per node (row-major: padded[d*PAD+p])
#define CHUNK 8192  // edges per XCD-replication group (R6 champion value)

typedef short short8 __attribute__((ext_vector_type(8)));
typedef float f32x4v __attribute__((ext_vector_type(4)));
typedef float f32x2v __attribute__((ext_vector_type(2)));
typedef int   i32x4v __attribute__((ext_vector_type(4)));

__device__ __forceinline__ ushort f2bf(float f) {
    uint b = __float_as_uint(f);
    uint r = (b + 0x7fffu + ((b >> 16) & 1u)) >> 16;
    return (ushort)r;
}
__device__ __forceinline__ float bflo(uint v) { return __uint_as_float(v << 16); }
__device__ __forceinline__ float bfhi(uint v) { return __uint_as_float(v & 0xffff0000u); }

// ---------------- K1: hybrid (NO LDS) ----------------
// Bucket blocks [0,nbB): 8 blocks per edge-chunk, one per XCD (blockIdx&7); each keeps
//   only dst in its XCD node range. Edge reads are NT (stream-once, 8x replicated) so
//   L2 stays reserved for cnt+padded (~825KB/XCD) -> dirtied lines written back ~once.
// GEMM blocks [nbB,..): tile 64r x 128c, K=128; wave = 32r x 64c. x NT-loaded
//   (stream-once), w cached (reused by all blocks), g NT-stored (consumed next kernel).
//   D layout (m89): row=(l>>4)*4+rr, col=(l&15).

__global__ __launch_bounds__(256) void hybrid(
    const int* __restrict__ src, const int* __restrict__ dst, int ne,
    int* __restrict__ cnt, ushort* __restrict__ padded, int nbB,
    const float* __restrict__ x, const float* __restrict__ w,
    ushort* __restrict__ g, int n)
{
    if (blockIdx.x < nbB) {
        const int grp = blockIdx.x >> 3;
        const int xcd = blockIdx.x & 7;
        const int sh  = (n + 7) >> 3;
        const int dlo = xcd * sh;
        const int dhi = (dlo + sh) < n ? (dlo + sh) : n;
        const int base = grp * CHUNK;
        const int lim  = (base + CHUNK) < ne ? (base + CHUNK) : ne;
        for (int e0 = base + threadIdx.x * 4; e0 < lim; e0 += 1024) {
            if (e0 + 3 < lim) {
                i32x4v s4 = __builtin_nontemporal_load(
                    reinterpret_cast<const i32x4v*>(&src[e0]));
                i32x4v d4 = __builtin_nontemporal_load(
                    reinterpret_cast<const i32x4v*>(&dst[e0]));
                if (d4.x >= dlo && d4.x < dhi) {
                    int p = atomicAdd(&cnt[d4.x], 1);
                    if (p < PAD) padded[(size_t)d4.x * PAD + p] = (ushort)s4.x;
                }
                if (d4.y >= dlo && d4.y < dhi) {
                    int p = atomicAdd(&cnt[d4.y], 1);
                    if (p < PAD) padded[(size_t)d4.y * PAD + p] = (ushort)s4.y;
                }
                if (d4.z >= dlo && d4.z < dhi) {
                    int p = atomicAdd(&cnt[d4.z], 1);
                    if (p < PAD) padded[(size_t)d4.z * PAD + p] = (ushort)s4.z;
                }
                if (d4.w >= dlo && d4.w < dhi) {
                    int p = atomicAdd(&cnt[d4.w], 1);
                    if (p < PAD) padded[(size_t)d4.w * PAD + p] = (ushort)s4.w;
                }
            } else {
                for (int e = e0; e < lim; ++e) {
                    int d = dst[e];
                    if (d >= dlo && d < dhi) {
                        int p = atomicAdd(&cnt[d], 1);
                        if (p < PAD) padded[(size_t)d * PAD + p] = (ushort)src[e];
                    }
                }
            }
        }
        return;
    }

    const int gb   = blockIdx.x - nbB;
    const int t    = threadIdx.x;
    const int lane = t & 63;
    const int wv   = t >> 6;
    const int wr   = wv >> 1, wc = wv & 1;
    const int l15  = lane & 15, kg = lane >> 4;
    const int row0 = gb * 64 + wr * 32;
    const int col0 = wc * 64;

    f32x4v acc[2][4];
    #pragma unroll
    for (int rt = 0; rt < 2; ++rt)
        #pragma unroll
        for (int ct = 0; ct < 4; ++ct)
            acc[rt][ct] = (f32x4v){0.f, 0.f, 0.f, 0.f};

    #pragma unroll
    for (int kt = 0; kt < 4; ++kt) {
        const int k0 = kt * 32 + kg * 8;
        short8 a[2];
        #pragma unroll
        for (int rt = 0; rt < 2; ++rt) {
            int row = row0 + rt * 16 + l15;
            row = row < n ? row : n - 1;                       // clamp (stores guarded)
            f32x4v p0 = __builtin_nontemporal_load(
                reinterpret_cast<const f32x4v*>(&x[(size_t)row * F + k0]));
            f32x4v p1 = __builtin_nontemporal_load(
                reinterpret_cast<const f32x4v*>(&x[(size_t)row * F + k0 + 4]));
            ushort u[8] = {f2bf(p0.x), f2bf(p0.y), f2bf(p0.z), f2bf(p0.w),
                           f2bf(p1.x), f2bf(p1.y), f2bf(p1.z), f2bf(p1.w)};
            a[rt] = *reinterpret_cast<short8*>(u);
        }
        short8 b[4];
        #pragma unroll
        for (int ct = 0; ct < 4; ++ct) {
            int col = col0 + ct * 16 + l15;
            ushort u[8];
            #pragma unroll
            for (int j = 0; j < 8; ++j)
                u[j] = f2bf(w[(size_t)(k0 + j) * F + col]);    // W[k][col], cached (reused)
            b[ct] = *reinterpret_cast<short8*>(u);
        }
        #pragma unroll
        for (int rt = 0; rt < 2; ++rt)
            #pragma unroll
            for (int ct = 0; ct < 4; ++ct)
                acc[rt][ct] = __builtin_amdgcn_mfma_f32_16x16x32_bf16(
                    a[rt], b[ct], acc[rt][ct], 0, 0, 0);
    }

    #pragma unroll
    for (int rt = 0; rt < 2; ++rt) {
        int rbase = row0 + rt * 16 + kg * 4;
        #pragma unroll
        for (int ct = 0; ct < 4; ++ct) {
            int col = col0 + ct * 16 + l15;
            #pragma unroll
            for (int rr = 0; rr < 4; ++rr) {
                int row = rbase + rr;
                if (row < n)
                    __builtin_nontemporal_store(f2bf(acc[rt][ct][rr]),
                                                &g[(size_t)row * F + col]);
            }
        }
    }
}

// ---------------- K2: gather, one wave per dst node ----------------
// out[v] = dinv[v] * ( dinv[v]*h[v] + sum_s dinv[s]*h[s] ) + bias;  dinv = rsqrt(cnt+1)

__global__ __launch_bounds__(256) void gather_bf16(
    const int* __restrict__ cnt, const ushort* __restrict__ padded,
    const ushort* __restrict__ g, const float* __restrict__ bias,
    float* __restrict__ out, int n)
{
    int wid  = (blockIdx.x * 256 + threadIdx.x) >> 6;
    int lane = threadIdx.x & 63;
    if (wid >= n) return;
    wid = __builtin_amdgcn_readfirstlane(wid);   // wave-uniform -> scalar loads
    const int c = lane * 2;

    int   cv = cnt[wid];
    float dv = rsqrtf((float)cv + 1.0f);
    uint self = *reinterpret_cast<const uint*>(&g[(size_t)wid * F + c]);
    float ax = dv * bflo(self), ay = dv * bfhi(self);

    int m = cv < PAD ? cv : PAD;
    const ushort* pl = padded + (size_t)wid * PAD;

    int j = 0;
    for (; j + 4 <= m; j += 4) {
        int s0 = pl[j + 0], s1 = pl[j + 1], s2 = pl[j + 2], s3 = pl[j + 3];
        float d0 = rsqrtf((float)cnt[s0] + 1.0f);
        float d1 = rsqrtf((float)cnt[s1] + 1.0f);
        float d2 = rsqrtf((float)cnt[s2] + 1.0f);
        float d3 = rsqrtf((float)cnt[s3] + 1.0f);
        uint v0 = *reinterpret_cast<const uint*>(&g[(size_t)s0 * F + c]);
        uint v1 = *reinterpret_cast<const uint*>(&g[(size_t)s1 * F + c]);
        uint v2 = *reinterpret_cast<const uint*>(&g[(size_t)s2 * F + c]);
        uint v3 = *reinterpret_cast<const uint*>(&g[(size_t)s3 * F + c]);
        ax = fmaf(d0, bflo(v0), ax); ay = fmaf(d0, bfhi(v0), ay);
        ax = fmaf(d1, bflo(v1), ax); ay = fmaf(d1, bfhi(v1), ay);
        ax = fmaf(d2, bflo(v2), ax); ay = fmaf(d2, bfhi(v2), ay);
        ax = fmaf(d3, bflo(v3), ax); ay = fmaf(d3, bfhi(v3), ay);
    }
    for (; j < m; ++j) {
        int s = pl[j];
        float ds = rsqrtf((float)cnt[s] + 1.0f);
        uint v = *reinterpret_cast<const uint*>(&g[(size_t)s * F + c]);
        ax = fmaf(ds, bflo(v), ax);
        ay = fmaf(ds, bfhi(v), ay);
    }

    float2 bb = *reinterpret_cast<const float2*>(&bias[c]);
    f32x2v o;
    o.x = fmaf(dv, ax, bb.x);
    o.y = fmaf(dv, ay, bb.y);
    __builtin_nontemporal_store(o, reinterpret_cast<f32x2v*>(&out[(size_t)wid * F + c]));
}

// ---------------- fallback path (fp32 atomics, minimal ws) ----------------

__global__ __launch_bounds__(256) void gemm_scale(
    const float* __restrict__ x, const float* __restrict__ w,
    const float* __restrict__ dinv, float* __restrict__ g, int n)
{
    __shared__ float sWl[F * F];
    __shared__ float sXl[8][F];
    for (int i = threadIdx.x; i < F * F; i += 256) sWl[i] = w[i];
    __syncthreads();
    const int r  = threadIdx.x >> 5;
    const int cg = threadIdx.x & 31;
    for (int row0 = blockIdx.x * 8; row0 < n; row0 += gridDim.x * 8) {
        {
            int t4 = threadIdx.x * 4;
            int rr = t4 >> 7, cc = t4 & (F - 1);
            if (row0 + rr < n) {
                float4 v = *reinterpret_cast<const float4*>(&x[(size_t)(row0 + rr) * F + cc]);
                *reinterpret_cast<float4*>(&sXl[rr][cc]) = v;
            }
        }
        __syncthreads();
        int row = row0 + r;
        if (row < n) {
            float4 acc = make_float4(0.f, 0.f, 0.f, 0.f);
            const float* xr = sXl[r];
            #pragma unroll 8
            for (int k = 0; k < F; ++k) {
                float  xv = xr[k];
                float4 wv = *reinterpret_cast<const float4*>(&sWl[k * F + cg * 4]);
                acc.x = fmaf(xv, wv.x, acc.x);
                acc.y = fmaf(xv, wv.y, acc.y);
                acc.z = fmaf(xv, wv.z, acc.z);
                acc.w = fmaf(xv, wv.w, acc.w);
            }
            float s = dinv[row];
            acc.x *= s; acc.y *= s; acc.z *= s; acc.w *= s;
            *reinterpret_cast<float4*>(&g[(size_t)row * F + cg * 4]) = acc;
        }
        __syncthreads();
    }
}

__global__ void init_degf(float* __restrict__ deg, int n) {
    int i = blockIdx.x * blockDim.x + threadIdx.x;
    if (i < n) deg[i] = 1.0f;
}
__global__ void count_degf(const int* __restrict__ dst, int ne, float* __restrict__ deg) {
    int e = blockIdx.x * blockDim.x + threadIdx.x;
    if (e < ne) atomicAdd(&deg[dst[e]], 1.0f);
}
__global__ void calc_dinvf(const float* __restrict__ deg, float* __restrict__ dinv, int n) {
    int i = blockIdx.x * blockDim.x + threadIdx.x;
    if (i < n) dinv[i] = rsqrtf(fmaxf(deg[i], 1e-12f));
}
__global__ __launch_bounds__(256) void scatter_edges(
    const int* __restrict__ src, const int* __restrict__ dst, int ne,
    const float* __restrict__ g, float* __restrict__ out)
{
    int gid  = (blockIdx.x * blockDim.x + threadIdx.x) >> 5;
    int lane = threadIdx.x & 31;
    if (gid >= ne) return;
    int s = src[gid], d = dst[gid];
    float4 v = *reinterpret_cast<const float4*>(&g[(size_t)s * F + lane * 4]);
    float* op = &out[(size_t)d * F + lane * 4];
    atomicAdd(op + 0, v.x);
    atomicAdd(op + 1, v.y);
    atomicAdd(op + 2, v.z);
    atomicAdd(op + 3, v.w);
}
__global__ __launch_bounds__(256) void finalize(
    float* __restrict__ out, const float* __restrict__ g,
    const float* __restrict__ dinv, const float* __restrict__ bias, int n)
{
    int i = blockIdx.x * blockDim.x + threadIdx.x;
    if (i >= n * 32) return;
    int row = i >> 5, c4 = i & 31;
    float  s = dinv[row];
    float4 o = *reinterpret_cast<float4*>(&out[(size_t)i * 4]);
    float4 gg = *reinterpret_cast<const float4*>(&g[(size_t)i * 4]);
    float4 b = *reinterpret_cast<const float4*>(&bias[c4 * 4]);
    o.x = fmaf(s, o.x + gg.x, b.x);
    o.y = fmaf(s, o.y + gg.y, b.y);
    o.z = fmaf(s, o.z + gg.z, b.z);
    o.w = fmaf(s, o.w + gg.w, b.w);
    *reinterpret_cast<float4*>(&out[(size_t)i * 4]) = o;
}

// ---------------- launcher ----------------

extern "C" void kernel_launch(void* const* d_in, const int* in_sizes, int n_in,
                              void* d_out, int out_size, void* d_ws, size_t ws_size,
                              hipStream_t stream) {
    const float* x     = (const float*)d_in[0];
    const int*   index = (const int*)d_in[1];
    const float* w     = (const float*)d_in[2];
    const float* bias  = (const float*)d_in[3];
    float*       out   = (float*)d_out;

    int n  = in_sizes[0] / F;   // 50000
    int ne = in_sizes[1] / 2;   // 625000
    const int* src = index;
    const int* dst = index + ne;

    // workspace layout (bytes)
    size_t b_cnt    = 0;
    size_t b_padded = (b_cnt + (size_t)n * 4 + 15) & ~(size_t)15;
    size_t b_g      = (b_padded + (size_t)n * PAD * 2 + 15) & ~(size_t)15;
    size_t need     = b_g + (size_t)n * F * 2;

    char* wsb = (char*)d_ws;
    int*    cnt    = (int*)(wsb + b_cnt);
    ushort* padded = (ushort*)(wsb + b_padded);
    ushort* g      = (ushort*)(wsb + b_g);

    int nbB = ((ne + CHUNK - 1) / CHUNK) * 8;             // 616 bucket blocks
    int nbG = (n + 63) / 64;                              // 782 gemm blocks

    if (ws_size >= need && n <= 65535) {
        hipMemsetAsync(cnt, 0, (size_t)n * 4, stream);
        hybrid<<<nbB + nbG, 256, 0, stream>>>(src, dst, ne, cnt, padded, nbB, x, w, g, n);
        int gb = (int)(((long long)n * 64 + 255) / 256);
        gather_bf16<<<gb, 256, 0, stream>>>(cnt, padded, g, bias, out, n);
    } else {
        // fallback: fp32 atomic path
        float* degf  = (float*)wsb;
        float* dinvf = (float*)wsb + n;
        float* gf    = (float*)wsb + 2 * n;
        int nb  = (n + 255) / 256;
        int nbE = (ne + 255) / 256;
        hipMemsetAsync(d_out, 0, (size_t)out_size * sizeof(float), stream);
        init_degf<<<nb, 256, 0, stream>>>(degf, n);
        count_degf<<<nbE, 256, 0, stream>>>(dst, ne, degf);
        calc_dinvf<<<nb, 256, 0, stream>>>(degf, dinvf, n);
        gemm_scale<<<(n + 7) / 8, 256, 0, stream>>>(x, w, dinvf, gf, n);
        int sc_blocks = (int)(((long long)ne * 32 + 255) / 256);
        scatter_edges<<<sc_blocks, 256, 0, stream>>>(src, dst, ne, gf, out);
        finalize<<<(n * 32 + 255) / 256, 256, 0, stream>>>(out, gf, dinvf, bias, n);
    }
}